// Round 1
// baseline (617.587 us; speedup 1.0000x reference)
//
#include <hip/hip_runtime.h>
#include <hip/hip_bf16.h>

#define EMBED_D   2048
#define N_EXP     64
#define K_TOP     8
#define BK        32
#define TOK_BLK   128
#define THREADS   512          // 8 waves
#define XS_STRIDE 129          // 129 mod 32 = 1 -> conflict-free column reads

struct Epi {
    float L[TOK_BLK][N_EXP + 1];   // logits then scores; +1 pad -> bank spread
    float invZ[TOK_BLK];
    float cnt[N_EXP];
    float colp[8][N_EXP];
};

#define SM_BYTES ((sizeof(Epi) > (BK * XS_STRIDE * 4)) ? sizeof(Epi) : (BK * XS_STRIDE * 4))

__global__ __launch_bounds__(THREADS, 2) void moe_gate_main(
    const float* __restrict__ X,   // [n_tok][2048]
    const float* __restrict__ W,   // [64][2048]
    float* __restrict__ out,       // [n_tok*8 idx][n_tok*8 w][1 aux]
    float* __restrict__ ws,        // [64 counts][64 score sums]
    int n_tok)
{
    __shared__ char smem_raw[SM_BYTES];
    float* xs = (float*)smem_raw;
    Epi*   ep = (Epi*)smem_raw;

    const int tid  = threadIdx.x;
    const int lane = tid & 63;
    const int wv   = __builtin_amdgcn_readfirstlane(tid >> 6);  // 0..7, wave-uniform
    const int e0   = wv << 3;                                    // expert base
    const int t0   = blockIdx.x * TOK_BLK;

    float acc0[8], acc1[8];
#pragma unroll
    for (int j = 0; j < 8; ++j) { acc0[j] = 0.f; acc1[j] = 0.f; }

    // staging assignment: two float4 per thread per chunk (128 rows x 32 cols)
    const int f0 = tid, f1 = THREADS + tid;
    const int m0 = f0 >> 3, kq0 = f0 & 7;      // row in tile, float4-col
    const int m1 = f1 >> 3, kq1 = f1 & 7;
    const float* xrow0 = X + (size_t)(t0 + m0) * EMBED_D + (kq0 << 2);
    const float* xrow1 = X + (size_t)(t0 + m1) * EMBED_D + (kq1 << 2);

    float4 p0 = *(const float4*)(xrow0);
    float4 p1 = *(const float4*)(xrow1);

    const float* wbase = W + (size_t)e0 * EMBED_D;   // wave-uniform

    const int NCHUNK = EMBED_D / BK;   // 64
    for (int c = 0; c < NCHUNK; ++c) {
        __syncthreads();
        // transpose-store staged chunk: xs[k][m]
#pragma unroll
        for (int j = 0; j < 4; ++j)
            xs[(kq0 * 4 + j) * XS_STRIDE + m0] = ((const float*)&p0)[j];
#pragma unroll
        for (int j = 0; j < 4; ++j)
            xs[(kq1 * 4 + j) * XS_STRIDE + m1] = ((const float*)&p1)[j];
        // prefetch next chunk (overlaps with compute below)
        if (c + 1 < NCHUNK) {
            p0 = *(const float4*)(xrow0 + (c + 1) * BK);
            p1 = *(const float4*)(xrow1 + (c + 1) * BK);
        }
        __syncthreads();

#pragma unroll
        for (int kk = 0; kk < BK / 4; ++kk) {
            float4 w4[8];
#pragma unroll
            for (int j = 0; j < 8; ++j)   // wave-uniform addr -> s_load_dwordx4
                w4[j] = *(const float4*)(wbase + (size_t)j * EMBED_D + c * BK + kk * 4);
#pragma unroll
            for (int k4 = 0; k4 < 4; ++k4) {
                const int k = kk * 4 + k4;
                const float x0 = xs[k * XS_STRIDE + lane];
                const float x1 = xs[k * XS_STRIDE + 64 + lane];
#pragma unroll
                for (int j = 0; j < 8; ++j) {
                    const float wval = ((const float*)&w4[j])[k4];
                    acc0[j] = fmaf(x0, wval, acc0[j]);
                    acc1[j] = fmaf(x1, wval, acc1[j]);
                }
            }
        }
    }

    __syncthreads();   // xs dead; reuse smem as Epi

    // scatter logits to LDS: L[token][expert]
#pragma unroll
    for (int j = 0; j < 8; ++j) {
        ep->L[lane][e0 + j]      = acc0[j];
        ep->L[64 + lane][e0 + j] = acc1[j];
    }
    if (tid < N_EXP) ep->cnt[tid] = 0.f;
    __syncthreads();

    // per-token softmax + top-8 (threads 0..127)
    if (tid < TOK_BLK) {
        const int t = tid;
        float mx = -1e30f;
        for (int e = 0; e < N_EXP; ++e) mx = fmaxf(mx, ep->L[t][e]);
        float Z = 0.f;
        float tv[K_TOP]; int ti[K_TOP];
#pragma unroll
        for (int j = 0; j < K_TOP; ++j) { tv[j] = -1e30f; ti[j] = 0; }
        for (int e = 0; e < N_EXP; ++e) {
            const float s = __expf(ep->L[t][e] - mx);
            ep->L[t][e] = s;                 // keep unnormalized score for Pi pass
            Z += s;
            float v = s; int id = e;
#pragma unroll
            for (int j = 0; j < K_TOP; ++j) {  // strict > : ties keep lower index
                if (v > tv[j]) {
                    float fv = tv[j]; tv[j] = v; v = fv;
                    int   fi = ti[j]; ti[j] = id; id = fi;
                }
            }
        }
        const float invZ = 1.0f / Z;
        ep->invZ[t] = invZ;
        const size_t ob = (size_t)(t0 + t) * K_TOP;
        const size_t woff = (size_t)n_tok * K_TOP;
#pragma unroll
        for (int j = 0; j < K_TOP; ++j) {
            out[ob + j]        = (float)ti[j];        // idx written as float
            out[woff + ob + j] = tv[j] * invZ;        // softmax weight
            atomicAdd(&ep->cnt[ti[j]], 1.0f);
        }
    }
    __syncthreads();

    // per-expert score column sums (Pi numerator): 8 groups x 16 tokens
    {
        const int e = tid & 63, g = tid >> 6;
        float s = 0.f;
#pragma unroll
        for (int i = 0; i < 16; ++i) {
            const int t = g * 16 + i;
            s += ep->L[t][e] * ep->invZ[t];
        }
        ep->colp[g][e] = s;
    }
    __syncthreads();
    if (tid < N_EXP) {
        float s = 0.f;
#pragma unroll
        for (int g = 0; g < 8; ++g) s += ep->colp[g][tid];
        atomicAdd(&ws[64 + tid], s);           // sum of scores per expert
        atomicAdd(&ws[tid], ep->cnt[tid]);     // assignment counts per expert
    }
}

__global__ void moe_aux(const float* __restrict__ ws, float* __restrict__ out, int n_tok)
{
    const int e = threadIdx.x;   // 64 threads
    const float counts = ws[e];
    const float ssum   = ws[64 + e];
    const float Pi = ssum / (float)n_tok;
    const float ce = counts / ((float)n_tok * (float)K_TOP);
    float term = Pi * ce * (float)N_EXP;
    for (int off = 32; off; off >>= 1) term += __shfl_down(term, off);
    if (e == 0) out[(size_t)2 * n_tok * K_TOP] = term * 0.01f;
}

extern "C" void kernel_launch(void* const* d_in, const int* in_sizes, int n_in,
                              void* d_out, int out_size, void* d_ws, size_t ws_size,
                              hipStream_t stream)
{
    const float* X = (const float*)d_in[0];
    const float* W = (const float*)d_in[1];
    float* out = (float*)d_out;
    float* ws  = (float*)d_ws;
    const int n_tok = in_sizes[0] / EMBED_D;   // 32768

    hipMemsetAsync(ws, 0, 2 * N_EXP * sizeof(float), stream);
    moe_gate_main<<<n_tok / TOK_BLK, THREADS, 0, stream>>>(X, W, out, ws, n_tok);
    moe_aux<<<1, 64, 0, stream>>>(ws, out, n_tok);
}

// Round 3
// 602.278 us; speedup vs baseline: 1.0254x; 1.0254x over previous
//
#include <hip/hip_runtime.h>
#include <hip/hip_bf16.h>

#define EMBED_D   2048
#define N_EXP     64
#define K_TOP     8
#define BK        64
#define TOK_BLK   64
#define THREADS   512          // 8 waves = 4 expert-groups x 2 k-halves
#define EPG       16           // experts per wave
#define XS_STRIDE 65           // 65 mod 32 = 1 -> <=2-way LDS aliasing (free)
#define NCHUNK    (EMBED_D / BK)   // 32

__global__ __launch_bounds__(THREADS, 4) void moe_gate_main(
    const float* __restrict__ X,   // [n_tok][2048]
    const float* __restrict__ W,   // [64][2048]
    float* __restrict__ out,       // [n_tok*8 idx][n_tok*8 w][1 aux]
    float* __restrict__ ws,        // [64 counts][64 score sums]
    int n_tok)
{
    // Disjoint LDS regions (no union, no double-buffer): 52.5 KB total.
    __shared__ float xs[BK][XS_STRIDE];               // 16640 B  X tile [k][tok]
    __shared__ float Lp[2][TOK_BLK][N_EXP + 1];       // 33280 B  partial logits per k-half
    __shared__ float sInvZ[TOK_BLK];
    __shared__ float sCnt[N_EXP];
    __shared__ float sColp[8][N_EXP];

    const int tid  = threadIdx.x;
    const int lane = tid & 63;                         // token within tile
    const int wv   = __builtin_amdgcn_readfirstlane(tid >> 6);  // 0..7 (R1-proven)
    const int eg   = wv & 3;                           // expert group
    const int kg   = wv >> 2;                          // k half (0/1)
    const int e0   = eg * EPG;
    const int t0   = blockIdx.x * TOK_BLK;

    float acc[EPG];
#pragma unroll
    for (int j = 0; j < EPG; ++j) acc[j] = 0.f;

    // staging: 64 tok x 64 k = 1024 float4; 512 threads -> 2 float4 each
    const int m0 = tid >> 4, kq = tid & 15;
    const int m1 = 32 + m0;
    const float* xr0 = X + (size_t)(t0 + m0) * EMBED_D + (kq << 2);
    const float* xr1 = X + (size_t)(t0 + m1) * EMBED_D + (kq << 2);
    float4 p0 = *(const float4*)xr0;
    float4 p1 = *(const float4*)xr1;

    const float* wbase = W + e0 * EMBED_D;   // wave-uniform -> s_load path

    for (int c = 0; c < NCHUNK; ++c) {
        __syncthreads();   // previous chunk's compute done -> xs writable
#pragma unroll
        for (int j = 0; j < 4; ++j) {
            xs[kq * 4 + j][m0] = ((const float*)&p0)[j];
            xs[kq * 4 + j][m1] = ((const float*)&p1)[j];
        }
        if (c + 1 < NCHUNK) {   // register prefetch of next chunk
            p0 = *(const float4*)(xr0 + (c + 1) * BK);
            p1 = *(const float4*)(xr1 + (c + 1) * BK);
        }
        __syncthreads();   // xs ready

        const int kb = c * BK + kg * 32;   // this wave's 32-k slice
#pragma unroll
        for (int kk = 0; kk < 8; ++kk) {
            float4 w4[EPG];
#pragma unroll
            for (int j = 0; j < EPG; ++j)   // uniform addr -> s_load_dwordx4
                w4[j] = *(const float4*)(wbase + j * EMBED_D + kb + kk * 4);
#pragma unroll
            for (int k4 = 0; k4 < 4; ++k4) {
                const float x = xs[kg * 32 + kk * 4 + k4][lane];
#pragma unroll
                for (int j = 0; j < EPG; ++j)
                    acc[j] = fmaf(x, ((const float*)&w4[j])[k4], acc[j]);
            }
        }
    }

    // scatter partial logits (Lp disjoint from xs -> no barrier needed first)
#pragma unroll
    for (int j = 0; j < EPG; ++j)
        Lp[kg][lane][e0 + j] = acc[j];
    if (tid < N_EXP) sCnt[tid] = 0.f;
    __syncthreads();

    // per-token: combine k-halves, softmax, top-8 (threads 0..63)
    if (tid < TOK_BLK) {
        const int t = tid;
        float mx = -1e30f;
        for (int e = 0; e < N_EXP; ++e) {
            const float l = Lp[0][t][e] + Lp[1][t][e];
            Lp[0][t][e] = l;
            mx = fmaxf(mx, l);
        }
        float Z = 0.f;
        float tv[K_TOP]; int ti[K_TOP];
#pragma unroll
        for (int j = 0; j < K_TOP; ++j) { tv[j] = -1e30f; ti[j] = 0; }
        for (int e = 0; e < N_EXP; ++e) {
            const float s = __expf(Lp[0][t][e] - mx);
            Lp[0][t][e] = s;                 // unnormalized score for Pi pass
            Z += s;
            float v = s; int id = e;
#pragma unroll
            for (int j = 0; j < K_TOP; ++j) {  // strict > : ties keep lower idx
                if (v > tv[j]) {
                    float fv = tv[j]; tv[j] = v; v = fv;
                    int   fi = ti[j]; ti[j] = id; id = fi;
                }
            }
        }
        const float invZ = 1.0f / Z;
        sInvZ[t] = invZ;
        const size_t ob = (size_t)(t0 + t) * K_TOP;
        const size_t wo = (size_t)n_tok * K_TOP;
#pragma unroll
        for (int j = 0; j < K_TOP; ++j) {
            out[ob + j]      = (float)ti[j];
            out[wo + ob + j] = tv[j] * invZ;
            atomicAdd(&sCnt[ti[j]], 1.0f);
        }
    }
    __syncthreads();

    // per-expert score sums (Pi numerator): 8 groups x 8 tokens
    {
        const int e = tid & 63, g = tid >> 6;
        float s = 0.f;
#pragma unroll
        for (int i = 0; i < 8; ++i) {
            const int t = g * 8 + i;
            s += Lp[0][t][e] * sInvZ[t];
        }
        sColp[g][e] = s;
    }
    __syncthreads();
    if (tid < N_EXP) {
        float s = 0.f;
#pragma unroll
        for (int g = 0; g < 8; ++g) s += sColp[g][tid];
        atomicAdd(&ws[64 + tid], s);
        atomicAdd(&ws[tid], sCnt[tid]);
    }
}

__global__ void moe_aux(const float* __restrict__ ws, float* __restrict__ out, int n_tok)
{
    const int e = threadIdx.x;   // 64 threads
    const float counts = ws[e];
    const float ssum   = ws[64 + e];
    const float Pi = ssum / (float)n_tok;
    const float ce = counts / ((float)n_tok * (float)K_TOP);
    float term = Pi * ce * (float)N_EXP;
    for (int off = 32; off; off >>= 1) term += __shfl_down(term, off);
    if (e == 0) out[(size_t)2 * n_tok * K_TOP] = term * 0.01f;
}

extern "C" void kernel_launch(void* const* d_in, const int* in_sizes, int n_in,
                              void* d_out, int out_size, void* d_ws, size_t ws_size,
                              hipStream_t stream)
{
    const float* X = (const float*)d_in[0];
    const float* W = (const float*)d_in[1];
    float* out = (float*)d_out;
    float* ws  = (float*)d_ws;
    const int n_tok = in_sizes[0] / EMBED_D;   // 32768

    hipMemsetAsync(ws, 0, 2 * N_EXP * sizeof(float), stream);
    moe_gate_main<<<n_tok / TOK_BLK, THREADS, 0, stream>>>(X, W, out, ws, n_tok);
    moe_aux<<<1, 64, 0, stream>>>(ws, out, n_tok);
}